// Round 2
// baseline (1369.338 us; speedup 1.0000x reference)
//
#include <hip/hip_runtime.h>

typedef float f32x4 __attribute__((ext_vector_type(4)));
typedef short bf16x8 __attribute__((ext_vector_type(8)));
typedef unsigned short u16x8 __attribute__((ext_vector_type(8)));
typedef unsigned short u16x4 __attribute__((ext_vector_type(4)));

#define KD 2048

static __device__ __forceinline__ unsigned short f2bf(float f) {
    __bf16 b = (__bf16)f;               // RNE
    return __builtin_bit_cast(unsigned short, b);
}
static __device__ __forceinline__ float bf2f(unsigned short h) {
    unsigned int u = ((unsigned int)h) << 16;
    return __builtin_bit_cast(float, u);
}

// ---------------- RoPE tables ----------------
__global__ void rope_tables(float* __restrict__ cosT, float* __restrict__ sinT) {
    int i = blockIdx.x * 256 + threadIdx.x;          // 2048*64 entries
    if (i >= 2048 * 64) return;
    int s = i >> 6, j = i & 63;
    float freq = exp2f(-(2.0f * (float)j / 128.0f) * 13.287712379549449f);
    float a = (float)s * freq;
    cosT[i] = cosf(a);
    sinT[i] = sinf(a);
}

// ---------------- fused GEMM: D[i][j] = sum_k A[i][k]*B[j][k], hi/lo split ----
// MODE 0: Q  (A=Wq, B=x)      -> RoPE+scale, bf16 hi->OutH, lo->OutL (B,H,S,dh)
// MODE 1: K  (A=Wk, B=x)      -> RoPE,       bf16 hi/lo
// MODE 2: V  (A=x,  B=Wv)     -> bf16 Vt (B,H,dh,S), hi only
// MODE 3: O  (A=Wo, B=attn bf16) -> fp32 (B,S,D); A split 2-term
template<int MODE>
__global__ __launch_bounds__(256)
void gemm_fused(const float* __restrict__ A, const void* __restrict__ Bsrc,
                void* __restrict__ OutH, void* __restrict__ OutL,
                const float* __restrict__ cosT, const float* __restrict__ sinT)
{
    constexpr bool B_BF16 = (MODE == 3);
    const int bi = blockIdx.x, bj = blockIdx.y;
    const int tid = threadIdx.x;
    const int lane = tid & 63;
    const int wid = tid >> 6;
    const int wm = wid >> 1, wn = wid & 1;
    const int lg = lane >> 4, lr = lane & 15;

    __shared__ unsigned short As_h[128 * 40];   // 32 k + 8 pad (80B stride)
    __shared__ unsigned short As_l[128 * 40];
    __shared__ unsigned short Bs_h[128 * 40];
    __shared__ unsigned short Bs_l[128 * 40];

    const int ra = tid >> 1;                  // 0..127
    const int ka = (tid & 1) * 16;            // 0 or 16
    const float* Ag = A + (size_t)(bi * 128 + ra) * KD + ka;
    const float* Bgf = nullptr;
    const unsigned short* Bgh = nullptr;
    if constexpr (!B_BF16) Bgf = (const float*)Bsrc + (size_t)(bj * 128 + ra) * KD + ka;
    else                   Bgh = (const unsigned short*)Bsrc;

    f32x4 acc[4][4];
#pragma unroll
    for (int i = 0; i < 4; ++i)
#pragma unroll
        for (int j = 0; j < 4; ++j) acc[i][j] = f32x4{0.f, 0.f, 0.f, 0.f};

    f32x4 avA[2][4], avB[2][4];
    u16x8 bvH[2][2];

    auto loadT = [&](int set, int k0) {
#pragma unroll
        for (int i = 0; i < 4; ++i) avA[set][i] = *(const f32x4*)(Ag + k0 + i * 4);
        if constexpr (!B_BF16) {
#pragma unroll
            for (int i = 0; i < 4; ++i) avB[set][i] = *(const f32x4*)(Bgf + k0 + i * 4);
        } else {
#pragma unroll
            for (int r = 0; r < 2; ++r) {
                int idx = tid + 256 * r;
                bvH[set][r] = *(const u16x8*)(Bgh + (size_t)(bj * 128 + (idx >> 2)) * KD + k0 + (idx & 3) * 8);
            }
        }
    };
    auto storeT = [&](int set) {
        u16x8 h0, h1, l0, l1;
#pragma unroll
        for (int i = 0; i < 4; ++i) {
            float a0 = avA[set][0][i], a1 = avA[set][1][i];
            float a2 = avA[set][2][i], a3 = avA[set][3][i];
            unsigned short h;
            h = f2bf(a0); h0[i]     = h; l0[i]     = f2bf(a0 - bf2f(h));
            h = f2bf(a1); h0[4 + i] = h; l0[4 + i] = f2bf(a1 - bf2f(h));
            h = f2bf(a2); h1[i]     = h; l1[i]     = f2bf(a2 - bf2f(h));
            h = f2bf(a3); h1[4 + i] = h; l1[4 + i] = f2bf(a3 - bf2f(h));
        }
        *(u16x8*)&As_h[ra * 40 + ka]     = h0;
        *(u16x8*)&As_h[ra * 40 + ka + 8] = h1;
        *(u16x8*)&As_l[ra * 40 + ka]     = l0;
        *(u16x8*)&As_l[ra * 40 + ka + 8] = l1;
        if constexpr (!B_BF16) {
            u16x8 g0, g1, m0, m1;
#pragma unroll
            for (int i = 0; i < 4; ++i) {
                float b0 = avB[set][0][i], b1 = avB[set][1][i];
                float b2 = avB[set][2][i], b3 = avB[set][3][i];
                unsigned short h;
                h = f2bf(b0); g0[i]     = h; m0[i]     = f2bf(b0 - bf2f(h));
                h = f2bf(b1); g0[4 + i] = h; m0[4 + i] = f2bf(b1 - bf2f(h));
                h = f2bf(b2); g1[i]     = h; m1[i]     = f2bf(b2 - bf2f(h));
                h = f2bf(b3); g1[4 + i] = h; m1[4 + i] = f2bf(b3 - bf2f(h));
            }
            *(u16x8*)&Bs_h[ra * 40 + ka]     = g0;
            *(u16x8*)&Bs_h[ra * 40 + ka + 8] = g1;
            *(u16x8*)&Bs_l[ra * 40 + ka]     = m0;
            *(u16x8*)&Bs_l[ra * 40 + ka + 8] = m1;
        } else {
#pragma unroll
            for (int r = 0; r < 2; ++r) {
                int idx = tid + 256 * r;
                *(u16x8*)&Bs_h[(idx >> 2) * 40 + (idx & 3) * 8] = bvH[set][r];
            }
        }
    };
    auto term = [&](const unsigned short* As_, const unsigned short* Bs_) {
        const unsigned short* Ap = &As_[(wm * 64 + lr) * 40 + lg * 8];
        const unsigned short* Bp = &Bs_[(wn * 64 + lr) * 40 + lg * 8];
        bf16x8 af[4], bff[4];
#pragma unroll
        for (int i = 0; i < 4; ++i) {
            af[i]  = *(const bf16x8*)(Ap + i * 16 * 40);
            bff[i] = *(const bf16x8*)(Bp + i * 16 * 40);
        }
#pragma unroll
        for (int mi = 0; mi < 4; ++mi)
#pragma unroll
            for (int ni = 0; ni < 4; ++ni)
                acc[mi][ni] = __builtin_amdgcn_mfma_f32_16x16x32_bf16(af[mi], bff[ni], acc[mi][ni], 0, 0, 0);
    };
    auto compute = [&]() {
        term(As_h, Bs_h);
        if constexpr (!B_BF16) {
            term(As_h, Bs_l);
            term(As_l, Bs_h);
        } else {
            term(As_l, Bs_h);
        }
    };

    loadT(0, 0);
#pragma unroll 1
    for (int kt2 = 0; kt2 < 32; ++kt2) {
        int k0 = kt2 * 64;
        loadT(1, k0 + 32);
        __syncthreads();
        storeT(0);
        __syncthreads();
        compute();
        if (k0 + 64 < KD) loadT(0, k0 + 64);
        __syncthreads();
        storeT(1);
        __syncthreads();
        compute();
    }

    if constexpr (MODE <= 1) {
        unsigned short* OH = (unsigned short*)OutH;
        unsigned short* OL = (unsigned short*)OutL;
        const float scale = (MODE == 0) ? 0.08838834764831845f : 1.0f;
#pragma unroll
        for (int mi = 0; mi < 4; ++mi) {
            int i0 = bi * 128 + wm * 64 + mi * 16 + lg * 4;  // dout, 4 consecutive
            int h = i0 >> 7, dd = i0 & 127;
            int jp = dd >> 1;
#pragma unroll
            for (int ni = 0; ni < 4; ++ni) {
                int jj = bj * 128 + wn * 64 + ni * 16 + lr;  // token
                int b = jj >> 11, s = jj & 2047;
                float c0 = cosT[s * 64 + jp],     s0 = sinT[s * 64 + jp];
                float c1 = cosT[s * 64 + jp + 1], s1 = sinT[s * 64 + jp + 1];
                f32x4 v = acc[mi][ni];
                float r0 = (v[0] * c0 - v[1] * s0) * scale;
                float r1 = (v[0] * s0 + v[1] * c0) * scale;
                float r2 = (v[2] * c1 - v[3] * s1) * scale;
                float r3 = (v[2] * s1 + v[3] * c1) * scale;
                unsigned short h0 = f2bf(r0), h1 = f2bf(r1), h2 = f2bf(r2), h3 = f2bf(r3);
                u16x4 ph = { h0, h1, h2, h3 };
                u16x4 pl = { f2bf(r0 - bf2f(h0)), f2bf(r1 - bf2f(h1)),
                             f2bf(r2 - bf2f(h2)), f2bf(r3 - bf2f(h3)) };
                size_t off = ((size_t)(b * 16 + h) * 2048 + s) * 128 + dd;
                *(u16x4*)&OH[off] = ph;
                *(u16x4*)&OL[off] = pl;
            }
        }
    } else if constexpr (MODE == 2) {
        unsigned short* O = (unsigned short*)OutH;
#pragma unroll
        for (int mi = 0; mi < 4; ++mi) {
            int i0 = bi * 128 + wm * 64 + mi * 16 + lg * 4;  // token, 4 consecutive
            int b = i0 >> 11, s = i0 & 2047;
#pragma unroll
            for (int ni = 0; ni < 4; ++ni) {
                int jj = bj * 128 + wn * 64 + ni * 16 + lr;  // dout
                int h = jj >> 7, dd = jj & 127;
                f32x4 v = acc[mi][ni];
                u16x4 pk = { f2bf(v[0]), f2bf(v[1]), f2bf(v[2]), f2bf(v[3]) };
                *(u16x4*)&O[((size_t)(b * 16 + h) * 128 + dd) * 2048 + s] = pk;
            }
        }
    } else {
        float* O = (float*)OutH;
#pragma unroll
        for (int mi = 0; mi < 4; ++mi) {
            int i0 = bi * 128 + wm * 64 + mi * 16 + lg * 4;  // dout, 4 consecutive
#pragma unroll
            for (int ni = 0; ni < 4; ++ni) {
                int jj = bj * 128 + wn * 64 + ni * 16 + lr;  // token
                *(f32x4*)&O[(size_t)jj * 2048 + i0] = acc[mi][ni];
            }
        }
    }
}

// ---------------- causal flash attention (hi/lo Q,K; split P) ----------------
// grid (32 qtiles, 64 bh); block 256 = 4 waves, wave w owns q rows qt*64+w*16..+15
__global__ __launch_bounds__(256)
void attn_kernel(const unsigned short* __restrict__ Qh, const unsigned short* __restrict__ Ql,
                 const unsigned short* __restrict__ Kh, const unsigned short* __restrict__ Kl,
                 const unsigned short* __restrict__ Vt,
                 unsigned short* __restrict__ Ob)
{
    const int qt = blockIdx.x;
    const int bh = blockIdx.y;
    const int tid = threadIdx.x;
    const int lane = tid & 63, w = tid >> 6;
    const int lg = lane >> 4, lr = lane & 15;

    __shared__ unsigned short Ksh[32 * 136];     // 128 d + 8 pad
    __shared__ unsigned short Ksl[32 * 136];
    __shared__ unsigned short Vs[128 * 40];      // 32 kv + 8 pad
    __shared__ unsigned short Psh[4][16 * 40];   // per-wave P relayout
    __shared__ unsigned short Psl[4][16 * 40];

    const int q = qt * 64 + w * 16 + lr;
    const unsigned short* Qph = Qh + ((size_t)bh * 2048 + q) * 128;
    const unsigned short* Qpl = Ql + ((size_t)bh * 2048 + q) * 128;
    bf16x8 qfh[4], qfl[4];
#pragma unroll
    for (int kk = 0; kk < 4; ++kk) {
        qfh[kk] = *(const bf16x8*)(Qph + kk * 32 + lg * 8);
        qfl[kk] = *(const bf16x8*)(Qpl + kk * 32 + lg * 8);
    }

    f32x4 o[8];
#pragma unroll
    for (int i = 0; i < 8; ++i) o[i] = f32x4{0.f, 0.f, 0.f, 0.f};
    float m_run = -1e30f, l_run = 0.f;
    const int wq_hi = qt * 64 + w * 16 + 15;
    const int nkv = 2 * (qt + 1);

    for (int kb = 0; kb < nkv; ++kb) {
        const int kv0 = kb * 32;
        __syncthreads();
#pragma unroll
        for (int r = 0; r < 2; ++r) {
            int idx = tid + 256 * r;
            size_t src = ((size_t)bh * 2048 + kv0 + (idx >> 4)) * 128 + (idx & 15) * 8;
            *(u16x8*)&Ksh[(idx >> 4) * 136 + (idx & 15) * 8] = *(const u16x8*)&Kh[src];
            *(u16x8*)&Ksl[(idx >> 4) * 136 + (idx & 15) * 8] = *(const u16x8*)&Kl[src];
        }
#pragma unroll
        for (int r = 0; r < 2; ++r) {
            int idx = tid + 256 * r;
            *(u16x8*)&Vs[(idx >> 2) * 40 + (idx & 3) * 8] =
                *(const u16x8*)&Vt[((size_t)bh * 128 + (idx >> 2)) * 2048 + kv0 + (idx & 3) * 8];
        }
        __syncthreads();
        if (kv0 <= wq_hi) {   // keep barrier counts aligned across waves
            // QK^T swapped: D[kv][q]; 3-term split
            f32x4 sc[2] = { f32x4{0.f,0.f,0.f,0.f}, f32x4{0.f,0.f,0.f,0.f} };
#pragma unroll
            for (int m2 = 0; m2 < 2; ++m2)
#pragma unroll
                for (int kk = 0; kk < 4; ++kk) {
                    bf16x8 kfh = *(const bf16x8*)&Ksh[(m2 * 16 + lr) * 136 + kk * 32 + lg * 8];
                    bf16x8 kfl = *(const bf16x8*)&Ksl[(m2 * 16 + lr) * 136 + kk * 32 + lg * 8];
                    sc[m2] = __builtin_amdgcn_mfma_f32_16x16x32_bf16(kfh, qfh[kk], sc[m2], 0, 0, 0);
                    sc[m2] = __builtin_amdgcn_mfma_f32_16x16x32_bf16(kfh, qfl[kk], sc[m2], 0, 0, 0);
                    sc[m2] = __builtin_amdgcn_mfma_f32_16x16x32_bf16(kfl, qfh[kk], sc[m2], 0, 0, 0);
                }
            float pmax = -1e30f;
#pragma unroll
            for (int m2 = 0; m2 < 2; ++m2)
#pragma unroll
                for (int rr = 0; rr < 4; ++rr) {
                    int kvg = kv0 + m2 * 16 + lg * 4 + rr;
                    float sv = (kvg <= q) ? sc[m2][rr] : -1e30f;
                    sc[m2][rr] = sv;
                    pmax = fmaxf(pmax, sv);
                }
            pmax = fmaxf(pmax, __shfl_xor(pmax, 16));
            pmax = fmaxf(pmax, __shfl_xor(pmax, 32));
            float mnew = fmaxf(m_run, pmax);
            float alpha = __expf(m_run - mnew);
            float psum = 0.f;
            u16x4 pqh[2], pql[2];
#pragma unroll
            for (int m2 = 0; m2 < 2; ++m2)
#pragma unroll
                for (int rr = 0; rr < 4; ++rr) {
                    float p = __expf(sc[m2][rr] - mnew);
                    unsigned short ph = f2bf(p);
                    unsigned short pl = f2bf(p - bf2f(ph));
                    pqh[m2][rr] = ph;
                    pql[m2][rr] = pl;
                    psum += bf2f(ph) + bf2f(pl);   // consistent with PV numerator
                }
            m_run = mnew;
            l_run = l_run * alpha + psum;
#pragma unroll
            for (int ni = 0; ni < 8; ++ni) {
                o[ni][0] *= alpha; o[ni][1] *= alpha;
                o[ni][2] *= alpha; o[ni][3] *= alpha;
            }
            // P: C-layout -> B-fragment layout via per-wave LDS (intra-wave)
            *(u16x4*)&Psh[w][lr * 40 + lg * 4]      = pqh[0];
            *(u16x4*)&Psh[w][lr * 40 + 16 + lg * 4] = pqh[1];
            *(u16x4*)&Psl[w][lr * 40 + lg * 4]      = pql[0];
            *(u16x4*)&Psl[w][lr * 40 + 16 + lg * 4] = pql[1];
            bf16x8 pfh = *(const bf16x8*)&Psh[w][lr * 40 + lg * 8];
            bf16x8 pfl = *(const bf16x8*)&Psl[w][lr * 40 + lg * 8];
            // PV swapped: O^T[d][q], A = Vt rows (d), B = P (2-term)
#pragma unroll
            for (int ni = 0; ni < 8; ++ni) {
                bf16x8 vf = *(const bf16x8*)&Vs[(ni * 16 + lr) * 40 + lg * 8];
                o[ni] = __builtin_amdgcn_mfma_f32_16x16x32_bf16(vf, pfh, o[ni], 0, 0, 0);
                o[ni] = __builtin_amdgcn_mfma_f32_16x16x32_bf16(vf, pfl, o[ni], 0, 0, 0);
            }
        }
    }
    l_run += __shfl_xor(l_run, 16);
    l_run += __shfl_xor(l_run, 32);
    float inv = 1.f / l_run;
    const int b = bh >> 4, h = bh & 15;
    unsigned short* Op = Ob + (((size_t)(b * 2048 + q) * 16 + h) * 128);
#pragma unroll
    for (int ni = 0; ni < 8; ++ni) {
        u16x4 pk = { f2bf(o[ni][0] * inv), f2bf(o[ni][1] * inv),
                     f2bf(o[ni][2] * inv), f2bf(o[ni][3] * inv) };
        *(u16x4*)&Op[ni * 16 + lg * 4] = pk;
    }
}

extern "C" void kernel_launch(void* const* d_in, const int* in_sizes, int n_in,
                              void* d_out, int out_size, void* d_ws, size_t ws_size,
                              hipStream_t stream) {
    const float* x  = (const float*)d_in[0];
    const float* Wq = (const float*)d_in[1];
    const float* Wk = (const float*)d_in[2];
    const float* Wv = (const float*)d_in[3];
    const float* Wo = (const float*)d_in[4];

    char* ws = (char*)d_ws;
    float* cosT = (float*)ws;                       // 512 KB
    float* sinT = cosT + 2048 * 64;                 // 512 KB
    unsigned short* Ql     = (unsigned short*)(ws + (1 << 20));
    unsigned short* Kl     = Ql + (size_t)16777216; // 33.55 MB each
    unsigned short* Vt     = Kl + (size_t)16777216;
    unsigned short* attn_b = Vt + (size_t)16777216; // total ws: ~135.3 MB

    // d_out (67.1 MB fp32) hosts Qh/Kh until the final GEMM overwrites it
    unsigned short* Qh = (unsigned short*)d_out;
    unsigned short* Kh = Qh + (size_t)16777216;

    rope_tables<<<dim3(512), 256, 0, stream>>>(cosT, sinT);
    gemm_fused<0><<<dim3(16, 64), 256, 0, stream>>>(Wq, x, Qh, Ql, cosT, sinT);
    gemm_fused<1><<<dim3(16, 64), 256, 0, stream>>>(Wk, x, Kh, Kl, cosT, sinT);
    gemm_fused<2><<<dim3(64, 16), 256, 0, stream>>>(x, Wv, Vt, nullptr, cosT, sinT);
    attn_kernel<<<dim3(32, 64), 256, 0, stream>>>(Qh, Ql, Kh, Kl, Vt, attn_b);
    gemm_fused<3><<<dim3(16, 64), 256, 0, stream>>>(Wo, attn_b, d_out, nullptr, cosT, sinT);
}

// Round 3
// 1045.110 us; speedup vs baseline: 1.3102x; 1.3102x over previous
//
#include <hip/hip_runtime.h>

typedef float f32x4 __attribute__((ext_vector_type(4)));
typedef short bf16x8 __attribute__((ext_vector_type(8)));
typedef unsigned short u16x8 __attribute__((ext_vector_type(8)));
typedef unsigned short u16x4 __attribute__((ext_vector_type(4)));

#define KD 2048

static __device__ __forceinline__ unsigned short f2bf(float f) {
    __bf16 b = (__bf16)f;               // RNE
    return __builtin_bit_cast(unsigned short, b);
}
static __device__ __forceinline__ float bf2f(unsigned short h) {
    unsigned int u = ((unsigned int)h) << 16;
    return __builtin_bit_cast(float, u);
}
// async global->LDS, 16B per lane (dest = wave-uniform base + lane*16, so pass
// per-lane linear lds ptr; swizzles are applied on the GLOBAL source side)
static __device__ __forceinline__ void gl16(const unsigned short* g, unsigned short* l) {
    __builtin_amdgcn_global_load_lds(
        (const __attribute__((address_space(1))) unsigned int*)g,
        (__attribute__((address_space(3))) unsigned int*)l, 16, 0, 0);
}

// ---------------- RoPE tables ----------------
__global__ void rope_tables(float* __restrict__ cosT, float* __restrict__ sinT) {
    int i = blockIdx.x * 256 + threadIdx.x;          // 2048*64 entries
    if (i >= 2048 * 64) return;
    int s = i >> 6, j = i & 63;
    float freq = exp2f(-(2.0f * (float)j / 128.0f) * 13.287712379549449f);
    float a = (float)s * freq;
    cosT[i] = cosf(a);
    sinT[i] = sinf(a);
}

// ---------------- fp32 -> bf16 hi(/lo) split ----------------
__global__ void presplit(const float* __restrict__ src, unsigned short* __restrict__ dh,
                         unsigned short* __restrict__ dl, int n4) {
    int i = blockIdx.x * 256 + threadIdx.x;
    if (i >= n4) return;
    f32x4 v = ((const f32x4*)src)[i];
    u16x4 h, l;
#pragma unroll
    for (int j = 0; j < 4; ++j) {
        unsigned short hh = f2bf(v[j]);
        h[j] = hh;
        l[j] = f2bf(v[j] - bf2f(hh));
    }
    ((u16x4*)dh)[i] = h;
    if (dl) ((u16x4*)dl)[i] = l;
}

// ---------------- GEMM v2: D[i][j] = sum_k A[i][k]*B[j][k] ----------------
// MODE 0: Q (A=Wq fp32 reg-split 3-term, B=xh/xl gload) -> RoPE+scale, Qh/Ql bf16
// MODE 1: K (A=Wk)                                      -> RoPE, Kh/Kl
// MODE 2: V (A=xh gload, B=Wvh gload, 1-term)           -> Vt bf16 (B,H,dh,S)
// MODE 3: O (A=Wo fp32 reg hi, B=attn_b bf16, 1-term)   -> fp32 (B,S,D)
template<int MODE>
__global__ __launch_bounds__(256)
void gemm2(const float* __restrict__ Af, const unsigned short* __restrict__ Abf,
           const unsigned short* __restrict__ Bh_g, const unsigned short* __restrict__ Bl_g,
           void* __restrict__ OutH, void* __restrict__ OutL,
           const float* __restrict__ cosT, const float* __restrict__ sinT)
{
    constexpr bool SPLIT = (MODE <= 1);      // 3-term
    constexpr bool A_REG = (MODE != 2);      // A staged from fp32 via regs
    constexpr int  ASTR  = A_REG ? 40 : 32;  // reg-path tiles padded, gload linear

    const int bi = blockIdx.x, bj = blockIdx.y;
    const int tid = threadIdx.x;
    const int lane = tid & 63;
    const int w = tid >> 6;
    const int wm = w >> 1, wn = w & 1;
    const int lg = lane >> 4, lr = lane & 15;

    __shared__ unsigned short As_h[128 * ASTR];
    __shared__ unsigned short As_l[SPLIT ? 128 * 40 : 8];
    __shared__ unsigned short Bs_h[128 * 32];
    __shared__ unsigned short Bs_l[SPLIT ? 128 * 32 : 8];

    const int ra = tid >> 1;                  // 0..127
    const int ka = (tid & 1) * 16;            // 0 or 16
    const float* Ag = A_REG ? (Af + (size_t)(bi * 128 + ra) * KD + ka) : nullptr;

    f32x4 acc[4][4];
#pragma unroll
    for (int i = 0; i < 4; ++i)
#pragma unroll
        for (int j = 0; j < 4; ++j) acc[i][j] = f32x4{0.f, 0.f, 0.f, 0.f};

    f32x4 avA[4];
    auto loadA = [&](int k0) {
        if constexpr (A_REG) {
#pragma unroll
            for (int i = 0; i < 4; ++i) avA[i] = *(const f32x4*)(Ag + k0 + i * 4);
        }
    };
    auto writeA = [&]() {
        if constexpr (A_REG) {
            u16x8 h0, h1;
            if constexpr (SPLIT) {
                u16x8 l0, l1;
#pragma unroll
                for (int i = 0; i < 4; ++i) {
                    unsigned short h;
                    h = f2bf(avA[0][i]); h0[i]     = h; l0[i]     = f2bf(avA[0][i] - bf2f(h));
                    h = f2bf(avA[1][i]); h0[4 + i] = h; l0[4 + i] = f2bf(avA[1][i] - bf2f(h));
                    h = f2bf(avA[2][i]); h1[i]     = h; l1[i]     = f2bf(avA[2][i] - bf2f(h));
                    h = f2bf(avA[3][i]); h1[4 + i] = h; l1[4 + i] = f2bf(avA[3][i] - bf2f(h));
                }
                *(u16x8*)&As_l[ra * 40 + ka]     = l0;
                *(u16x8*)&As_l[ra * 40 + ka + 8] = l1;
            } else {
#pragma unroll
                for (int i = 0; i < 4; ++i) {
                    h0[i]     = f2bf(avA[0][i]);
                    h0[4 + i] = f2bf(avA[1][i]);
                    h1[i]     = f2bf(avA[2][i]);
                    h1[4 + i] = f2bf(avA[3][i]);
                }
            }
            *(u16x8*)&As_h[ra * 40 + ka]     = h0;
            *(u16x8*)&As_h[ra * 40 + ka + 8] = h1;
        }
    };
    auto stageB = [&](int k0) {
#pragma unroll
        for (int q2 = 0; q2 < 2; ++q2) {
            const int seg = w * 2 + q2;                 // 0..7
            const int row = seg * 16 + (lane >> 2);     // 0..127
            const int loff = seg * 512 + lane * 8;      // shorts
            const size_t gs = (size_t)(bj * 128 + row) * KD + k0 + (lane & 3) * 8;
            gl16(Bh_g + gs, &Bs_h[loff]);
            if constexpr (SPLIT) gl16(Bl_g + gs, &Bs_l[loff]);
            if constexpr (!A_REG) {
                const size_t ga = (size_t)(bi * 128 + row) * KD + k0 + (lane & 3) * 8;
                gl16(Abf + ga, &As_h[loff]);
            }
        }
    };
    auto term = [&](const unsigned short* As_, const unsigned short* Bs_) {
        const unsigned short* Ap = &As_[(wm * 64 + lr) * ASTR + lg * 8];
        const unsigned short* Bp = &Bs_[(wn * 64 + lr) * 32 + lg * 8];
        bf16x8 af[4], bf[4];
#pragma unroll
        for (int i = 0; i < 4; ++i) {
            af[i] = *(const bf16x8*)(Ap + i * 16 * ASTR);
            bf[i] = *(const bf16x8*)(Bp + i * 16 * 32);
        }
#pragma unroll
        for (int mi = 0; mi < 4; ++mi)
#pragma unroll
            for (int ni = 0; ni < 4; ++ni)
                acc[mi][ni] = __builtin_amdgcn_mfma_f32_16x16x32_bf16(af[mi], bf[ni], acc[mi][ni], 0, 0, 0);
    };

    loadA(0);
#pragma unroll 1
    for (int kt = 0; kt < 64; ++kt) {
        const int k0 = kt * 32;
        __syncthreads();                 // previous compute done; LDS reusable
        writeA();
        stageB(k0);
        if (kt < 63) loadA(k0 + 32);     // prefetch next A (overlaps compute)
        __syncthreads();                 // staging visible (vmcnt+lgkm drained)
        term(As_h, Bs_h);
        if constexpr (SPLIT) {
            const unsigned short* Ap = &As_l[0];
            term(As_h, Bs_l);
            term(Ap,   Bs_h);
        }
    }

    if constexpr (MODE <= 1) {
        unsigned short* OH = (unsigned short*)OutH;
        unsigned short* OL = (unsigned short*)OutL;
        const float scale = (MODE == 0) ? 0.08838834764831845f : 1.0f;
#pragma unroll
        for (int mi = 0; mi < 4; ++mi) {
            int i0 = bi * 128 + wm * 64 + mi * 16 + lg * 4;  // dout, 4 consecutive
            int h = i0 >> 7, dd = i0 & 127;
            int jp = dd >> 1;
#pragma unroll
            for (int ni = 0; ni < 4; ++ni) {
                int jj = bj * 128 + wn * 64 + ni * 16 + lr;  // token
                int b = jj >> 11, s = jj & 2047;
                float c0 = cosT[s * 64 + jp],     s0 = sinT[s * 64 + jp];
                float c1 = cosT[s * 64 + jp + 1], s1 = sinT[s * 64 + jp + 1];
                f32x4 v = acc[mi][ni];
                float r0 = (v[0] * c0 - v[1] * s0) * scale;
                float r1 = (v[0] * s0 + v[1] * c0) * scale;
                float r2 = (v[2] * c1 - v[3] * s1) * scale;
                float r3 = (v[2] * s1 + v[3] * c1) * scale;
                unsigned short h0 = f2bf(r0), h1 = f2bf(r1), h2 = f2bf(r2), h3 = f2bf(r3);
                u16x4 ph = { h0, h1, h2, h3 };
                u16x4 pl = { f2bf(r0 - bf2f(h0)), f2bf(r1 - bf2f(h1)),
                             f2bf(r2 - bf2f(h2)), f2bf(r3 - bf2f(h3)) };
                size_t off = ((size_t)(b * 16 + h) * 2048 + s) * 128 + dd;
                *(u16x4*)&OH[off] = ph;
                *(u16x4*)&OL[off] = pl;
            }
        }
    } else if constexpr (MODE == 2) {
        unsigned short* O = (unsigned short*)OutH;
#pragma unroll
        for (int mi = 0; mi < 4; ++mi) {
            int i0 = bi * 128 + wm * 64 + mi * 16 + lg * 4;  // token, 4 consecutive
            int b = i0 >> 11, s = i0 & 2047;
#pragma unroll
            for (int ni = 0; ni < 4; ++ni) {
                int jj = bj * 128 + wn * 64 + ni * 16 + lr;  // dout
                int h = jj >> 7, dd = jj & 127;
                f32x4 v = acc[mi][ni];
                u16x4 pk = { f2bf(v[0]), f2bf(v[1]), f2bf(v[2]), f2bf(v[3]) };
                *(u16x4*)&O[((size_t)(b * 16 + h) * 128 + dd) * 2048 + s] = pk;
            }
        }
    } else {
        float* O = (float*)OutH;
#pragma unroll
        for (int mi = 0; mi < 4; ++mi) {
            int i0 = bi * 128 + wm * 64 + mi * 16 + lg * 4;  // dout, 4 consecutive
#pragma unroll
            for (int ni = 0; ni < 4; ++ni) {
                int jj = bj * 128 + wn * 64 + ni * 16 + lr;  // token
                *(f32x4*)&O[(size_t)jj * 2048 + i0] = acc[mi][ni];
            }
        }
    }
}

// ---------------- causal flash attention v2 ----------------
// 1024 blocks (remapped: long qt first, bh grouped per XCD); 4 waves;
// wave owns 32 q rows; KVBLK=32; K tiles XOR-swizzled ((row&7)<<4) via
// pre-swizzled global source + swizzled ds_read; dbuf issue-early staging.
__global__ __launch_bounds__(256)
void attn2(const unsigned short* __restrict__ Qh, const unsigned short* __restrict__ Ql,
           const unsigned short* __restrict__ Kh, const unsigned short* __restrict__ Kl,
           const unsigned short* __restrict__ Vt, unsigned short* __restrict__ Ob)
{
    const int bid = blockIdx.x;
    const int slot = bid >> 3;
    const int bh = (bid & 7) + 8 * (slot & 7);   // xcd-grouped by bh%8
    const int qt = 15 - (slot >> 3);             // longest blocks dispatch first
    const int tid = threadIdx.x;
    const int lane = tid & 63, w = tid >> 6;
    const int lg = lane >> 4, lr = lane & 15;

    __shared__ unsigned short Ksh[2][32 * 128];  // 8KB x2
    __shared__ unsigned short Ksl[2][32 * 128];
    __shared__ unsigned short Vs [2][128 * 32];  // [d][kv]
    __shared__ unsigned short Ps [4][32 * 32];   // per-wave P relay

    const int qbase = qt * 128 + w * 32;
    const int qmaxw = qbase + 31;

    bf16x8 qfh[2][4], qfl[2][4];
#pragma unroll
    for (int qg = 0; qg < 2; ++qg) {
        const size_t qoff = ((size_t)bh * 2048 + qbase + qg * 16 + lr) * 128;
#pragma unroll
        for (int kk = 0; kk < 4; ++kk) {
            qfh[qg][kk] = *(const bf16x8*)(Qh + qoff + kk * 32 + lg * 8);
            qfl[qg][kk] = *(const bf16x8*)(Ql + qoff + kk * 32 + lg * 8);
        }
    }

    f32x4 o[8][2];
#pragma unroll
    for (int i = 0; i < 8; ++i)
#pragma unroll
        for (int qg = 0; qg < 2; ++qg) o[i][qg] = f32x4{0.f, 0.f, 0.f, 0.f};
    float m_run[2] = { -1e30f, -1e30f }, l_run[2] = { 0.f, 0.f };

    const int nkv = 4 * (qt + 1);

    auto stage = [&](int t) {
        const int buf = t & 1;
        const int kv0 = t * 32;
#pragma unroll
        for (int q2 = 0; q2 < 2; ++q2) {
            const int seg = w * 2 + q2;                          // 0..7
            {   // K hi/lo: rows 256B -> swizzle granule ^ (row&7)
                const int row = seg * 4 + (lane >> 4);
                const int gcol = 8 * ((lane & 15) ^ (row & 7));
                const size_t gs = ((size_t)bh * 2048 + kv0 + row) * 128 + gcol;
                const int loff = seg * 512 + lane * 8;
                gl16(Kh + gs, &Ksh[buf][loff]);
                gl16(Kl + gs, &Ksl[buf][loff]);
            }
            {   // V: rows 64B -> swizzle granule ^ (row&3)
                const int row = seg * 16 + (lane >> 2);          // d 0..127
                const int gcol = 8 * ((lane & 3) ^ (row & 3));
                const size_t gs = ((size_t)bh * 128 + row) * 2048 + kv0 + gcol;
                gl16(Vt + gs, &Vs[buf][seg * 512 + lane * 8]);
            }
        }
    };

    stage(0);
    __syncthreads();

#pragma unroll 1
    for (int t = 0; t < nkv; ++t) {
        if (t + 1 < nkv) stage(t + 1);           // issue-early into other buffer
        const int buf = t & 1;
        const int kv0 = t * 32;
        if (kv0 <= qmaxw) {
            f32x4 sc[2][2];
#pragma unroll
            for (int m2 = 0; m2 < 2; ++m2)
#pragma unroll
                for (int qg = 0; qg < 2; ++qg) sc[m2][qg] = f32x4{0.f, 0.f, 0.f, 0.f};
#pragma unroll
            for (int m2 = 0; m2 < 2; ++m2)
#pragma unroll
                for (int kk = 0; kk < 4; ++kk) {
                    const int go = 8 * ((4 * kk + lg) ^ (lr & 7));
                    bf16x8 kfh = *(const bf16x8*)&Ksh[buf][(m2 * 16 + lr) * 128 + go];
                    bf16x8 kfl = *(const bf16x8*)&Ksl[buf][(m2 * 16 + lr) * 128 + go];
#pragma unroll
                    for (int qg = 0; qg < 2; ++qg) {
                        sc[m2][qg] = __builtin_amdgcn_mfma_f32_16x16x32_bf16(kfh, qfh[qg][kk], sc[m2][qg], 0, 0, 0);
                        sc[m2][qg] = __builtin_amdgcn_mfma_f32_16x16x32_bf16(kfh, qfl[qg][kk], sc[m2][qg], 0, 0, 0);
                        sc[m2][qg] = __builtin_amdgcn_mfma_f32_16x16x32_bf16(kfl, qfh[qg][kk], sc[m2][qg], 0, 0, 0);
                    }
                }
#pragma unroll
            for (int qg = 0; qg < 2; ++qg) {
                const int q = qbase + qg * 16 + lr;
                float pmax = -1e30f;
#pragma unroll
                for (int m2 = 0; m2 < 2; ++m2)
#pragma unroll
                    for (int rr = 0; rr < 4; ++rr) {
                        int kvg = kv0 + m2 * 16 + lg * 4 + rr;
                        float sv = (kvg <= q) ? sc[m2][qg][rr] : -1e30f;
                        sc[m2][qg][rr] = sv;
                        pmax = fmaxf(pmax, sv);
                    }
                pmax = fmaxf(pmax, __shfl_xor(pmax, 16));
                pmax = fmaxf(pmax, __shfl_xor(pmax, 32));
                float mnew = fmaxf(m_run[qg], pmax);
                float alpha = __expf(m_run[qg] - mnew);
                float psum = 0.f;
                u16x4 pq[2];
#pragma unroll
                for (int m2 = 0; m2 < 2; ++m2)
#pragma unroll
                    for (int rr = 0; rr < 4; ++rr) {
                        float p = __expf(sc[m2][qg][rr] - mnew);
                        unsigned short ph = f2bf(p);
                        pq[m2][rr] = ph;
                        psum += bf2f(ph);        // consistent with PV numerator
                    }
                m_run[qg] = mnew;
                l_run[qg] = l_run[qg] * alpha + psum;
#pragma unroll
                for (int ni = 0; ni < 8; ++ni) {
                    o[ni][qg][0] *= alpha; o[ni][qg][1] *= alpha;
                    o[ni][qg][2] *= alpha; o[ni][qg][3] *= alpha;
                }
                *(u16x4*)&Ps[w][(qg * 16 + lr) * 32 + lg * 4]      = pq[0];
                *(u16x4*)&Ps[w][(qg * 16 + lr) * 32 + 16 + lg * 4] = pq[1];
            }
            bf16x8 pf0 = *(const bf16x8*)&Ps[w][lr * 32 + lg * 8];
            bf16x8 pf1 = *(const bf16x8*)&Ps[w][(16 + lr) * 32 + lg * 8];
#pragma unroll
            for (int ni = 0; ni < 8; ++ni) {
                bf16x8 vf = *(const bf16x8*)&Vs[buf][(ni * 16 + lr) * 32 + 8 * (lg ^ (lr & 3))];
                o[ni][0] = __builtin_amdgcn_mfma_f32_16x16x32_bf16(vf, pf0, o[ni][0], 0, 0, 0);
                o[ni][1] = __builtin_amdgcn_mfma_f32_16x16x32_bf16(vf, pf1, o[ni][1], 0, 0, 0);
            }
        }
        __syncthreads();
    }

    const int b = bh >> 4, h = bh & 15;
#pragma unroll
    for (int qg = 0; qg < 2; ++qg) {
        float l = l_run[qg];
        l += __shfl_xor(l, 16);
        l += __shfl_xor(l, 32);
        float inv = 1.f / l;
        const int q = qbase + qg * 16 + lr;
        unsigned short* Op = Ob + (((size_t)(b * 2048 + q) * 16 + h) * 128);
#pragma unroll
        for (int ni = 0; ni < 8; ++ni) {
            u16x4 pk = { f2bf(o[ni][qg][0] * inv), f2bf(o[ni][qg][1] * inv),
                         f2bf(o[ni][qg][2] * inv), f2bf(o[ni][qg][3] * inv) };
            *(u16x4*)&Op[ni * 16 + lg * 4] = pk;
        }
    }
}

extern "C" void kernel_launch(void* const* d_in, const int* in_sizes, int n_in,
                              void* d_out, int out_size, void* d_ws, size_t ws_size,
                              hipStream_t stream) {
    const float* x  = (const float*)d_in[0];
    const float* Wq = (const float*)d_in[1];
    const float* Wk = (const float*)d_in[2];
    const float* Wv = (const float*)d_in[3];
    const float* Wo = (const float*)d_in[4];

    char* ws = (char*)d_ws;
    float* cosT = (float*)ws;                                   // 512 KB
    float* sinT = cosT + 2048 * 64;                             // 512 KB
    unsigned short* xh  = (unsigned short*)(ws + (1 << 20));    // 32 MB
    unsigned short* xl  = xh  + (size_t)16777216;               // 32 MB
    unsigned short* Wvh = xl  + (size_t)16777216;               // 8 MB
    unsigned short* Ql  = Wvh + (size_t)4194304;                // 32 MB
    unsigned short* Kl  = Ql  + (size_t)16777216;               // 32 MB  (ws ~137 MB)

    // aliases (lifetimes disjoint): Vt overwrites xl after K-GEMM;
    // attn_b overwrites xh after V-GEMM.
    unsigned short* Vt     = xl;
    unsigned short* attn_b = xh;

    // d_out (67 MB fp32) hosts Qh/Kh until the final GEMM overwrites it
    unsigned short* Qh = (unsigned short*)d_out;
    unsigned short* Kh = Qh + (size_t)16777216;

    rope_tables<<<dim3(512), 256, 0, stream>>>(cosT, sinT);
    presplit<<<dim3(16384), 256, 0, stream>>>(x, xh, xl, 4194304);
    presplit<<<dim3(4096), 256, 0, stream>>>(Wv, Wvh, nullptr, 1048576);

    gemm2<0><<<dim3(16, 64), 256, 0, stream>>>(Wq, nullptr, xh, xl, Qh, Ql, cosT, sinT);
    gemm2<1><<<dim3(16, 64), 256, 0, stream>>>(Wk, nullptr, xh, xl, Kh, Kl, cosT, sinT);
    gemm2<2><<<dim3(64, 16), 256, 0, stream>>>(nullptr, xh, Wvh, nullptr, Vt, nullptr, cosT, sinT);
    attn2<<<dim3(1024), 256, 0, stream>>>(Qh, Ql, Kh, Kl, Vt, attn_b);
    gemm2<3><<<dim3(16, 64), 256, 0, stream>>>(Wo, nullptr, attn_b, nullptr, d_out, nullptr, cosT, sinT);
}

// Round 4
// 1041.710 us; speedup vs baseline: 1.3145x; 1.0033x over previous
//
#include <hip/hip_runtime.h>

typedef float f32x4 __attribute__((ext_vector_type(4)));
typedef short bf16x8 __attribute__((ext_vector_type(8)));
typedef unsigned short u16x8 __attribute__((ext_vector_type(8)));
typedef unsigned short u16x4 __attribute__((ext_vector_type(4)));

#define KD 2048

static __device__ __forceinline__ unsigned short f2bf(float f) {
    __bf16 b = (__bf16)f;               // RNE
    return __builtin_bit_cast(unsigned short, b);
}
static __device__ __forceinline__ float bf2f(unsigned short h) {
    unsigned int u = ((unsigned int)h) << 16;
    return __builtin_bit_cast(float, u);
}
// async global->LDS, 16B per lane (dest = wave-uniform base + lane*16, so pass
// per-lane linear lds ptr; swizzles are applied on the GLOBAL source side)
static __device__ __forceinline__ void gl16(const unsigned short* g, unsigned short* l) {
    __builtin_amdgcn_global_load_lds(
        (const __attribute__((address_space(1))) unsigned int*)g,
        (__attribute__((address_space(3))) unsigned int*)l, 16, 0, 0);
}

// ---------------- RoPE tables ----------------
__global__ void rope_tables(float* __restrict__ cosT, float* __restrict__ sinT) {
    int i = blockIdx.x * 256 + threadIdx.x;          // 2048*64 entries
    if (i >= 2048 * 64) return;
    int s = i >> 6, j = i & 63;
    float freq = exp2f(-(2.0f * (float)j / 128.0f) * 13.287712379549449f);
    float a = (float)s * freq;
    cosT[i] = cosf(a);
    sinT[i] = sinf(a);
}

// ---------------- fp32 -> bf16 hi(/lo) split ----------------
__global__ void presplit(const float* __restrict__ src, unsigned short* __restrict__ dh,
                         unsigned short* __restrict__ dl, int n4) {
    int i = blockIdx.x * 256 + threadIdx.x;
    if (i >= n4) return;
    f32x4 v = ((const f32x4*)src)[i];
    u16x4 h, l;
#pragma unroll
    for (int j = 0; j < 4; ++j) {
        unsigned short hh = f2bf(v[j]);
        h[j] = hh;
        l[j] = f2bf(v[j] - bf2f(hh));
    }
    ((u16x4*)dh)[i] = h;
    if (dl) ((u16x4*)dl)[i] = l;
}

// ---------------- GEMM v2: D[i][j] = sum_k A[i][k]*B[j][k] ----------------
// MODE 0: Q (A=Wq fp32 reg-split 3-term, B=xh/xl gload) -> RoPE+scale, Qh/Ql bf16
// MODE 1: K (A=Wk)                                      -> RoPE, Kh/Kl
// MODE 2: V (A=xh gload, B=Wvh gload, 1-term)           -> Vt bf16 (B,H,dh,S)
// MODE 3: O (A=Wo fp32 reg hi, B=attn_b bf16, 1-term)   -> fp32 (B,S,D)
template<int MODE>
__global__ __launch_bounds__(256)
void gemm2(const float* __restrict__ Af, const unsigned short* __restrict__ Abf,
           const unsigned short* __restrict__ Bh_g, const unsigned short* __restrict__ Bl_g,
           void* __restrict__ OutH, void* __restrict__ OutL,
           const float* __restrict__ cosT, const float* __restrict__ sinT)
{
    constexpr bool SPLIT = (MODE <= 1);      // 3-term
    constexpr bool A_REG = (MODE != 2);      // A staged from fp32 via regs
    constexpr int  ASTR  = A_REG ? 40 : 32;  // reg-path tiles padded, gload linear

    const int bi = blockIdx.x, bj = blockIdx.y;
    const int tid = threadIdx.x;
    const int lane = tid & 63;
    const int w = tid >> 6;
    const int wm = w >> 1, wn = w & 1;
    const int lg = lane >> 4, lr = lane & 15;

    __shared__ unsigned short As_h[128 * ASTR];
    __shared__ unsigned short As_l[SPLIT ? 128 * 40 : 8];
    __shared__ unsigned short Bs_h[128 * 32];
    __shared__ unsigned short Bs_l[SPLIT ? 128 * 32 : 8];

    const int ra = tid >> 1;                  // 0..127
    const int ka = (tid & 1) * 16;            // 0 or 16
    const float* Ag = A_REG ? (Af + (size_t)(bi * 128 + ra) * KD + ka) : nullptr;

    f32x4 acc[4][4];
#pragma unroll
    for (int i = 0; i < 4; ++i)
#pragma unroll
        for (int j = 0; j < 4; ++j) acc[i][j] = f32x4{0.f, 0.f, 0.f, 0.f};

    f32x4 avA[4];
    auto loadA = [&](int k0) {
        if constexpr (A_REG) {
#pragma unroll
            for (int i = 0; i < 4; ++i) avA[i] = *(const f32x4*)(Ag + k0 + i * 4);
        }
    };
    auto writeA = [&]() {
        if constexpr (A_REG) {
            u16x8 h0, h1;
            if constexpr (SPLIT) {
                u16x8 l0, l1;
#pragma unroll
                for (int i = 0; i < 4; ++i) {
                    unsigned short h;
                    h = f2bf(avA[0][i]); h0[i]     = h; l0[i]     = f2bf(avA[0][i] - bf2f(h));
                    h = f2bf(avA[1][i]); h0[4 + i] = h; l0[4 + i] = f2bf(avA[1][i] - bf2f(h));
                    h = f2bf(avA[2][i]); h1[i]     = h; l1[i]     = f2bf(avA[2][i] - bf2f(h));
                    h = f2bf(avA[3][i]); h1[4 + i] = h; l1[4 + i] = f2bf(avA[3][i] - bf2f(h));
                }
                *(u16x8*)&As_l[ra * 40 + ka]     = l0;
                *(u16x8*)&As_l[ra * 40 + ka + 8] = l1;
            } else {
#pragma unroll
                for (int i = 0; i < 4; ++i) {
                    h0[i]     = f2bf(avA[0][i]);
                    h0[4 + i] = f2bf(avA[1][i]);
                    h1[i]     = f2bf(avA[2][i]);
                    h1[4 + i] = f2bf(avA[3][i]);
                }
            }
            *(u16x8*)&As_h[ra * 40 + ka]     = h0;
            *(u16x8*)&As_h[ra * 40 + ka + 8] = h1;
        }
    };
    auto stageB = [&](int k0) {
#pragma unroll
        for (int q2 = 0; q2 < 2; ++q2) {
            const int seg = w * 2 + q2;                 // 0..7
            const int row = seg * 16 + (lane >> 2);     // 0..127
            const int loff = seg * 512 + lane * 8;      // shorts
            const size_t gs = (size_t)(bj * 128 + row) * KD + k0 + (lane & 3) * 8;
            gl16(Bh_g + gs, &Bs_h[loff]);
            if constexpr (SPLIT) gl16(Bl_g + gs, &Bs_l[loff]);
            if constexpr (!A_REG) {
                const size_t ga = (size_t)(bi * 128 + row) * KD + k0 + (lane & 3) * 8;
                gl16(Abf + ga, &As_h[loff]);
            }
        }
    };
    auto term = [&](const unsigned short* As_, const unsigned short* Bs_) {
        const unsigned short* Ap = &As_[(wm * 64 + lr) * ASTR + lg * 8];
        const unsigned short* Bp = &Bs_[(wn * 64 + lr) * 32 + lg * 8];
        bf16x8 af[4], bf[4];
#pragma unroll
        for (int i = 0; i < 4; ++i) {
            af[i] = *(const bf16x8*)(Ap + i * 16 * ASTR);
            bf[i] = *(const bf16x8*)(Bp + i * 16 * 32);
        }
#pragma unroll
        for (int mi = 0; mi < 4; ++mi)
#pragma unroll
            for (int ni = 0; ni < 4; ++ni)
                acc[mi][ni] = __builtin_amdgcn_mfma_f32_16x16x32_bf16(af[mi], bf[ni], acc[mi][ni], 0, 0, 0);
    };

    loadA(0);
#pragma unroll 1
    for (int kt = 0; kt < 64; ++kt) {
        const int k0 = kt * 32;
        __syncthreads();                 // previous compute done; LDS reusable
        writeA();
        stageB(k0);
        if (kt < 63) loadA(k0 + 32);     // prefetch next A (overlaps compute)
        __syncthreads();                 // staging visible (vmcnt+lgkm drained)
        term(As_h, Bs_h);
        if constexpr (SPLIT) {
            const unsigned short* Ap = &As_l[0];
            term(As_h, Bs_l);
            term(Ap,   Bs_h);
        }
    }

    if constexpr (MODE <= 1) {
        unsigned short* OH = (unsigned short*)OutH;
        unsigned short* OL = (unsigned short*)OutL;
        const float scale = (MODE == 0) ? 0.08838834764831845f : 1.0f;
#pragma unroll
        for (int mi = 0; mi < 4; ++mi) {
            int i0 = bi * 128 + wm * 64 + mi * 16 + lg * 4;  // dout, 4 consecutive
            int h = i0 >> 7, dd = i0 & 127;
            int jp = dd >> 1;
#pragma unroll
            for (int ni = 0; ni < 4; ++ni) {
                int jj = bj * 128 + wn * 64 + ni * 16 + lr;  // token
                int b = jj >> 11, s = jj & 2047;
                float c0 = cosT[s * 64 + jp],     s0 = sinT[s * 64 + jp];
                float c1 = cosT[s * 64 + jp + 1], s1 = sinT[s * 64 + jp + 1];
                f32x4 v = acc[mi][ni];
                float r0 = (v[0] * c0 - v[1] * s0) * scale;
                float r1 = (v[0] * s0 + v[1] * c0) * scale;
                float r2 = (v[2] * c1 - v[3] * s1) * scale;
                float r3 = (v[2] * s1 + v[3] * c1) * scale;
                unsigned short h0 = f2bf(r0), h1 = f2bf(r1), h2 = f2bf(r2), h3 = f2bf(r3);
                u16x4 ph = { h0, h1, h2, h3 };
                u16x4 pl = { f2bf(r0 - bf2f(h0)), f2bf(r1 - bf2f(h1)),
                             f2bf(r2 - bf2f(h2)), f2bf(r3 - bf2f(h3)) };
                size_t off = ((size_t)(b * 16 + h) * 2048 + s) * 128 + dd;
                *(u16x4*)&OH[off] = ph;
                *(u16x4*)&OL[off] = pl;
            }
        }
    } else if constexpr (MODE == 2) {
        unsigned short* O = (unsigned short*)OutH;
#pragma unroll
        for (int mi = 0; mi < 4; ++mi) {
            int i0 = bi * 128 + wm * 64 + mi * 16 + lg * 4;  // token, 4 consecutive
            int b = i0 >> 11, s = i0 & 2047;
#pragma unroll
            for (int ni = 0; ni < 4; ++ni) {
                int jj = bj * 128 + wn * 64 + ni * 16 + lr;  // dout
                int h = jj >> 7, dd = jj & 127;
                f32x4 v = acc[mi][ni];
                u16x4 pk = { f2bf(v[0]), f2bf(v[1]), f2bf(v[2]), f2bf(v[3]) };
                *(u16x4*)&O[((size_t)(b * 16 + h) * 128 + dd) * 2048 + s] = pk;
            }
        }
    } else {
        float* O = (float*)OutH;
#pragma unroll
        for (int mi = 0; mi < 4; ++mi) {
            int i0 = bi * 128 + wm * 64 + mi * 16 + lg * 4;  // dout, 4 consecutive
#pragma unroll
            for (int ni = 0; ni < 4; ++ni) {
                int jj = bj * 128 + wn * 64 + ni * 16 + lr;  // token
                *(f32x4*)&O[(size_t)jj * 2048 + i0] = acc[mi][ni];
            }
        }
    }
}

// ---------------- causal flash attention v2 ----------------
// 1024 blocks (remapped: long qt first, bh grouped per XCD); 4 waves;
// wave owns 32 q rows; KVBLK=32; K tiles XOR-swizzled ((row&7)<<4) via
// pre-swizzled global source + swizzled ds_read; dbuf issue-early staging.
__global__ __launch_bounds__(256)
void attn2(const unsigned short* __restrict__ Qh, const unsigned short* __restrict__ Ql,
           const unsigned short* __restrict__ Kh, const unsigned short* __restrict__ Kl,
           const unsigned short* __restrict__ Vt, unsigned short* __restrict__ Ob)
{
    const int bid = blockIdx.x;
    const int slot = bid >> 3;
    const int bh = (bid & 7) + 8 * (slot & 7);   // xcd-grouped by bh%8
    const int qt = 15 - (slot >> 3);             // longest blocks dispatch first
    const int tid = threadIdx.x;
    const int lane = tid & 63, w = tid >> 6;
    const int lg = lane >> 4, lr = lane & 15;

    __shared__ unsigned short Ksh[2][32 * 128];  // 8KB x2
    __shared__ unsigned short Ksl[2][32 * 128];
    __shared__ unsigned short Vs [2][128 * 32];  // [d][kv]
    __shared__ unsigned short Ps [4][32 * 32];   // per-wave P relay

    const int qbase = qt * 128 + w * 32;
    const int qmaxw = qbase + 31;

    bf16x8 qfh[2][4], qfl[2][4];
#pragma unroll
    for (int qg = 0; qg < 2; ++qg) {
        const size_t qoff = ((size_t)bh * 2048 + qbase + qg * 16 + lr) * 128;
#pragma unroll
        for (int kk = 0; kk < 4; ++kk) {
            qfh[qg][kk] = *(const bf16x8*)(Qh + qoff + kk * 32 + lg * 8);
            qfl[qg][kk] = *(const bf16x8*)(Ql + qoff + kk * 32 + lg * 8);
        }
    }

    f32x4 o[8][2];
#pragma unroll
    for (int i = 0; i < 8; ++i)
#pragma unroll
        for (int qg = 0; qg < 2; ++qg) o[i][qg] = f32x4{0.f, 0.f, 0.f, 0.f};
    float m_run[2] = { -1e30f, -1e30f }, l_run[2] = { 0.f, 0.f };

    const int nkv = 4 * (qt + 1);

    auto stage = [&](int t) {
        const int buf = t & 1;
        const int kv0 = t * 32;
#pragma unroll
        for (int q2 = 0; q2 < 2; ++q2) {
            const int seg = w * 2 + q2;                          // 0..7
            {   // K hi/lo: rows 256B -> swizzle granule ^ (row&7)
                const int row = seg * 4 + (lane >> 4);
                const int gcol = 8 * ((lane & 15) ^ (row & 7));
                const size_t gs = ((size_t)bh * 2048 + kv0 + row) * 128 + gcol;
                const int loff = seg * 512 + lane * 8;
                gl16(Kh + gs, &Ksh[buf][loff]);
                gl16(Kl + gs, &Ksl[buf][loff]);
            }
            {   // V: rows 64B -> swizzle granule ^ (row&3)
                const int row = seg * 16 + (lane >> 2);          // d 0..127
                const int gcol = 8 * ((lane & 3) ^ (row & 3));
                const size_t gs = ((size_t)bh * 128 + row) * 2048 + kv0 + gcol;
                gl16(Vt + gs, &Vs[buf][seg * 512 + lane * 8]);
            }
        }
    };

    stage(0);
    __syncthreads();

#pragma unroll 1
    for (int t = 0; t < nkv; ++t) {
        if (t + 1 < nkv) stage(t + 1);           // issue-early into other buffer
        const int buf = t & 1;
        const int kv0 = t * 32;
        if (kv0 <= qmaxw) {
            f32x4 sc[2][2];
#pragma unroll
            for (int m2 = 0; m2 < 2; ++m2)
#pragma unroll
                for (int qg = 0; qg < 2; ++qg) sc[m2][qg] = f32x4{0.f, 0.f, 0.f, 0.f};
#pragma unroll
            for (int m2 = 0; m2 < 2; ++m2)
#pragma unroll
                for (int kk = 0; kk < 4; ++kk) {
                    const int go = 8 * ((4 * kk + lg) ^ (lr & 7));
                    bf16x8 kfh = *(const bf16x8*)&Ksh[buf][(m2 * 16 + lr) * 128 + go];
                    bf16x8 kfl = *(const bf16x8*)&Ksl[buf][(m2 * 16 + lr) * 128 + go];
#pragma unroll
                    for (int qg = 0; qg < 2; ++qg) {
                        sc[m2][qg] = __builtin_amdgcn_mfma_f32_16x16x32_bf16(kfh, qfh[qg][kk], sc[m2][qg], 0, 0, 0);
                        sc[m2][qg] = __builtin_amdgcn_mfma_f32_16x16x32_bf16(kfh, qfl[qg][kk], sc[m2][qg], 0, 0, 0);
                        sc[m2][qg] = __builtin_amdgcn_mfma_f32_16x16x32_bf16(kfl, qfh[qg][kk], sc[m2][qg], 0, 0, 0);
                    }
                }
#pragma unroll
            for (int qg = 0; qg < 2; ++qg) {
                const int q = qbase + qg * 16 + lr;
                float pmax = -1e30f;
#pragma unroll
                for (int m2 = 0; m2 < 2; ++m2)
#pragma unroll
                    for (int rr = 0; rr < 4; ++rr) {
                        int kvg = kv0 + m2 * 16 + lg * 4 + rr;
                        float sv = (kvg <= q) ? sc[m2][qg][rr] : -1e30f;
                        sc[m2][qg][rr] = sv;
                        pmax = fmaxf(pmax, sv);
                    }
                pmax = fmaxf(pmax, __shfl_xor(pmax, 16));
                pmax = fmaxf(pmax, __shfl_xor(pmax, 32));
                float mnew = fmaxf(m_run[qg], pmax);
                float alpha = __expf(m_run[qg] - mnew);
                float psum = 0.f;
                u16x4 pq[2];
#pragma unroll
                for (int m2 = 0; m2 < 2; ++m2)
#pragma unroll
                    for (int rr = 0; rr < 4; ++rr) {
                        float p = __expf(sc[m2][qg][rr] - mnew);
                        unsigned short ph = f2bf(p);
                        pq[m2][rr] = ph;
                        psum += bf2f(ph);        // consistent with PV numerator
                    }
                m_run[qg] = mnew;
                l_run[qg] = l_run[qg] * alpha + psum;
#pragma unroll
                for (int ni = 0; ni < 8; ++ni) {
                    o[ni][qg][0] *= alpha; o[ni][qg][1] *= alpha;
                    o[ni][qg][2] *= alpha; o[ni][qg][3] *= alpha;
                }
                *(u16x4*)&Ps[w][(qg * 16 + lr) * 32 + lg * 4]      = pq[0];
                *(u16x4*)&Ps[w][(qg * 16 + lr) * 32 + 16 + lg * 4] = pq[1];
            }
            bf16x8 pf0 = *(const bf16x8*)&Ps[w][lr * 32 + lg * 8];
            bf16x8 pf1 = *(const bf16x8*)&Ps[w][(16 + lr) * 32 + lg * 8];
#pragma unroll
            for (int ni = 0; ni < 8; ++ni) {
                bf16x8 vf = *(const bf16x8*)&Vs[buf][(ni * 16 + lr) * 32 + 8 * (lg ^ (lr & 3))];
                o[ni][0] = __builtin_amdgcn_mfma_f32_16x16x32_bf16(vf, pf0, o[ni][0], 0, 0, 0);
                o[ni][1] = __builtin_amdgcn_mfma_f32_16x16x32_bf16(vf, pf1, o[ni][1], 0, 0, 0);
            }
        }
        __syncthreads();
    }

    const int b = bh >> 4, h = bh & 15;
#pragma unroll
    for (int qg = 0; qg < 2; ++qg) {
        float l = l_run[qg];
        l += __shfl_xor(l, 16);
        l += __shfl_xor(l, 32);
        float inv = 1.f / l;
        const int q = qbase + qg * 16 + lr;
        unsigned short* Op = Ob + (((size_t)(b * 2048 + q) * 16 + h) * 128);
#pragma unroll
        for (int ni = 0; ni < 8; ++ni) {
            u16x4 pk = { f2bf(o[ni][qg][0] * inv), f2bf(o[ni][qg][1] * inv),
                         f2bf(o[ni][qg][2] * inv), f2bf(o[ni][qg][3] * inv) };
            *(u16x4*)&Op[ni * 16 + lg * 4] = pk;
        }
    }
}

extern "C" void kernel_launch(void* const* d_in, const int* in_sizes, int n_in,
                              void* d_out, int out_size, void* d_ws, size_t ws_size,
                              hipStream_t stream) {
    const float* x  = (const float*)d_in[0];
    const float* Wq = (const float*)d_in[1];
    const float* Wk = (const float*)d_in[2];
    const float* Wv = (const float*)d_in[3];
    const float* Wo = (const float*)d_in[4];

    char* ws = (char*)d_ws;
    float* cosT = (float*)ws;                                   // 512 KB
    float* sinT = cosT + 2048 * 64;                             // 512 KB
    unsigned short* xh  = (unsigned short*)(ws + (1 << 20));    // 32 MB
    unsigned short* xl  = xh  + (size_t)16777216;               // 32 MB
    unsigned short* Wvh = xl  + (size_t)16777216;               // 8 MB
    unsigned short* Ql  = Wvh + (size_t)4194304;                // 32 MB
    unsigned short* Kl  = Ql  + (size_t)16777216;               // 32 MB  (ws ~137 MB)

    // aliases (lifetimes disjoint): Vt overwrites xl after K-GEMM;
    // attn_b overwrites xh after V-GEMM.
    unsigned short* Vt     = xl;
    unsigned short* attn_b = xh;

    // d_out (67 MB fp32) hosts Qh/Kh until the final GEMM overwrites it
    unsigned short* Qh = (unsigned short*)d_out;
    unsigned short* Kh = Qh + (size_t)16777216;

    rope_tables<<<dim3(512), 256, 0, stream>>>(cosT, sinT);
    presplit<<<dim3(16384), 256, 0, stream>>>(x, xh, xl, 4194304);
    presplit<<<dim3(4096), 256, 0, stream>>>(Wv, Wvh, nullptr, 1048576);

    gemm2<0><<<dim3(16, 64), 256, 0, stream>>>(Wq, nullptr, xh, xl, Qh, Ql, cosT, sinT);
    gemm2<1><<<dim3(16, 64), 256, 0, stream>>>(Wk, nullptr, xh, xl, Kh, Kl, cosT, sinT);
    gemm2<2><<<dim3(64, 16), 256, 0, stream>>>(nullptr, xh, Wvh, nullptr, Vt, nullptr, cosT, sinT);
    attn2<<<dim3(1024), 256, 0, stream>>>(Qh, Ql, Kh, Kl, Vt, attn_b);
    gemm2<3><<<dim3(16, 64), 256, 0, stream>>>(Wo, nullptr, attn_b, nullptr, d_out, nullptr, cosT, sinT);
}

// Round 5
// 1041.436 us; speedup vs baseline: 1.3149x; 1.0003x over previous
//
#include <hip/hip_runtime.h>

typedef float f32x4 __attribute__((ext_vector_type(4)));
typedef short bf16x8 __attribute__((ext_vector_type(8)));
typedef unsigned short u16x8 __attribute__((ext_vector_type(8)));
typedef unsigned short u16x4 __attribute__((ext_vector_type(4)));

#define KD 2048

static __device__ __forceinline__ unsigned short f2bf(float f) {
    __bf16 b = (__bf16)f;               // RNE
    return __builtin_bit_cast(unsigned short, b);
}
static __device__ __forceinline__ float bf2f(unsigned short h) {
    unsigned int u = ((unsigned int)h) << 16;
    return __builtin_bit_cast(float, u);
}
// async global->LDS, 16B per lane (dest = wave-uniform base + lane*16, so pass
// per-lane linear lds ptr; swizzles are applied on the GLOBAL source side)
static __device__ __forceinline__ void gl16(const unsigned short* g, unsigned short* l) {
    __builtin_amdgcn_global_load_lds(
        (const __attribute__((address_space(1))) unsigned int*)g,
        (__attribute__((address_space(3))) unsigned int*)l, 16, 0, 0);
}

// ---------------- RoPE tables ----------------
__global__ void rope_tables(float* __restrict__ cosT, float* __restrict__ sinT) {
    int i = blockIdx.x * 256 + threadIdx.x;          // 2048*64 entries
    if (i >= 2048 * 64) return;
    int s = i >> 6, j = i & 63;
    float freq = exp2f(-(2.0f * (float)j / 128.0f) * 13.287712379549449f);
    float a = (float)s * freq;
    cosT[i] = cosf(a);
    sinT[i] = sinf(a);
}

// ---------------- fp32 -> bf16 hi(/lo) split ----------------
__global__ void presplit(const float* __restrict__ src, unsigned short* __restrict__ dh,
                         unsigned short* __restrict__ dl, int n4) {
    int i = blockIdx.x * 256 + threadIdx.x;
    if (i >= n4) return;
    f32x4 v = ((const f32x4*)src)[i];
    u16x4 h, l;
#pragma unroll
    for (int j = 0; j < 4; ++j) {
        unsigned short hh = f2bf(v[j]);
        h[j] = hh;
        l[j] = f2bf(v[j] - bf2f(hh));
    }
    ((u16x4*)dh)[i] = h;
    if (dl) ((u16x4*)dl)[i] = l;
}

// ---------------- GEMM v2: D[i][j] = sum_k A[i][k]*B[j][k] ----------------
// MODE 0: Q (A=Wq fp32 reg-split 3-term, B=xh/xl gload) -> RoPE+scale, Qh/Ql bf16
// MODE 1: K (A=Wk)                                      -> RoPE, Kh/Kl
// MODE 2: V (A=xh gload, B=Wvh gload, 1-term)           -> Vt bf16 (B,H,dh,S)
// MODE 3: O (A=Wo fp32 reg hi, B=attn_b bf16, 1-term)   -> fp32 (B,S,D)
template<int MODE>
__global__ __launch_bounds__(256)
void gemm2(const float* __restrict__ Af, const unsigned short* __restrict__ Abf,
           const unsigned short* __restrict__ Bh_g, const unsigned short* __restrict__ Bl_g,
           void* __restrict__ OutH, void* __restrict__ OutL,
           const float* __restrict__ cosT, const float* __restrict__ sinT)
{
    constexpr bool SPLIT = (MODE <= 1);      // 3-term
    constexpr bool A_REG = (MODE != 2);      // A staged from fp32 via regs
    constexpr int  ASTR  = A_REG ? 40 : 32;  // reg-path tiles padded, gload linear

    const int bi = blockIdx.x, bj = blockIdx.y;
    const int tid = threadIdx.x;
    const int lane = tid & 63;
    const int w = tid >> 6;
    const int wm = w >> 1, wn = w & 1;
    const int lg = lane >> 4, lr = lane & 15;

    __shared__ unsigned short As_h[128 * ASTR];
    __shared__ unsigned short As_l[SPLIT ? 128 * 40 : 8];
    __shared__ unsigned short Bs_h[128 * 32];
    __shared__ unsigned short Bs_l[SPLIT ? 128 * 32 : 8];

    const int ra = tid >> 1;                  // 0..127
    const int ka = (tid & 1) * 16;            // 0 or 16
    const float* Ag = A_REG ? (Af + (size_t)(bi * 128 + ra) * KD + ka) : nullptr;

    f32x4 acc[4][4];
#pragma unroll
    for (int i = 0; i < 4; ++i)
#pragma unroll
        for (int j = 0; j < 4; ++j) acc[i][j] = f32x4{0.f, 0.f, 0.f, 0.f};

    f32x4 avA[4];
    auto loadA = [&](int k0) {
        if constexpr (A_REG) {
#pragma unroll
            for (int i = 0; i < 4; ++i) avA[i] = *(const f32x4*)(Ag + k0 + i * 4);
        }
    };
    auto writeA = [&]() {
        if constexpr (A_REG) {
            u16x8 h0, h1;
            if constexpr (SPLIT) {
                u16x8 l0, l1;
#pragma unroll
                for (int i = 0; i < 4; ++i) {
                    unsigned short h;
                    h = f2bf(avA[0][i]); h0[i]     = h; l0[i]     = f2bf(avA[0][i] - bf2f(h));
                    h = f2bf(avA[1][i]); h0[4 + i] = h; l0[4 + i] = f2bf(avA[1][i] - bf2f(h));
                    h = f2bf(avA[2][i]); h1[i]     = h; l1[i]     = f2bf(avA[2][i] - bf2f(h));
                    h = f2bf(avA[3][i]); h1[4 + i] = h; l1[4 + i] = f2bf(avA[3][i] - bf2f(h));
                }
                *(u16x8*)&As_l[ra * 40 + ka]     = l0;
                *(u16x8*)&As_l[ra * 40 + ka + 8] = l1;
            } else {
#pragma unroll
                for (int i = 0; i < 4; ++i) {
                    h0[i]     = f2bf(avA[0][i]);
                    h0[4 + i] = f2bf(avA[1][i]);
                    h1[i]     = f2bf(avA[2][i]);
                    h1[4 + i] = f2bf(avA[3][i]);
                }
            }
            *(u16x8*)&As_h[ra * 40 + ka]     = h0;
            *(u16x8*)&As_h[ra * 40 + ka + 8] = h1;
        }
    };
    auto stageB = [&](int k0) {
#pragma unroll
        for (int q2 = 0; q2 < 2; ++q2) {
            const int seg = w * 2 + q2;                 // 0..7
            const int row = seg * 16 + (lane >> 2);     // 0..127
            const int loff = seg * 512 + lane * 8;      // shorts
            const size_t gs = (size_t)(bj * 128 + row) * KD + k0 + (lane & 3) * 8;
            gl16(Bh_g + gs, &Bs_h[loff]);
            if constexpr (SPLIT) gl16(Bl_g + gs, &Bs_l[loff]);
            if constexpr (!A_REG) {
                const size_t ga = (size_t)(bi * 128 + row) * KD + k0 + (lane & 3) * 8;
                gl16(Abf + ga, &As_h[loff]);
            }
        }
    };
    auto term = [&](const unsigned short* As_, const unsigned short* Bs_) {
        const unsigned short* Ap = &As_[(wm * 64 + lr) * ASTR + lg * 8];
        const unsigned short* Bp = &Bs_[(wn * 64 + lr) * 32 + lg * 8];
        bf16x8 af[4], bf[4];
#pragma unroll
        for (int i = 0; i < 4; ++i) {
            af[i] = *(const bf16x8*)(Ap + i * 16 * ASTR);
            bf[i] = *(const bf16x8*)(Bp + i * 16 * 32);
        }
#pragma unroll
        for (int mi = 0; mi < 4; ++mi)
#pragma unroll
            for (int ni = 0; ni < 4; ++ni)
                acc[mi][ni] = __builtin_amdgcn_mfma_f32_16x16x32_bf16(af[mi], bf[ni], acc[mi][ni], 0, 0, 0);
    };

    loadA(0);
#pragma unroll 1
    for (int kt = 0; kt < 64; ++kt) {
        const int k0 = kt * 32;
        __syncthreads();                 // previous compute done; LDS reusable
        writeA();
        stageB(k0);
        if (kt < 63) loadA(k0 + 32);     // prefetch next A (overlaps compute)
        __syncthreads();                 // staging visible (vmcnt+lgkm drained)
        term(As_h, Bs_h);
        if constexpr (SPLIT) {
            const unsigned short* Ap = &As_l[0];
            term(As_h, Bs_l);
            term(Ap,   Bs_h);
        }
    }

    if constexpr (MODE <= 1) {
        unsigned short* OH = (unsigned short*)OutH;
        unsigned short* OL = (unsigned short*)OutL;
        const float scale = (MODE == 0) ? 0.08838834764831845f : 1.0f;
#pragma unroll
        for (int mi = 0; mi < 4; ++mi) {
            int i0 = bi * 128 + wm * 64 + mi * 16 + lg * 4;  // dout, 4 consecutive
            int h = i0 >> 7, dd = i0 & 127;
            int jp = dd >> 1;
#pragma unroll
            for (int ni = 0; ni < 4; ++ni) {
                int jj = bj * 128 + wn * 64 + ni * 16 + lr;  // token
                int b = jj >> 11, s = jj & 2047;
                float c0 = cosT[s * 64 + jp],     s0 = sinT[s * 64 + jp];
                float c1 = cosT[s * 64 + jp + 1], s1 = sinT[s * 64 + jp + 1];
                f32x4 v = acc[mi][ni];
                float r0 = (v[0] * c0 - v[1] * s0) * scale;
                float r1 = (v[0] * s0 + v[1] * c0) * scale;
                float r2 = (v[2] * c1 - v[3] * s1) * scale;
                float r3 = (v[2] * s1 + v[3] * c1) * scale;
                unsigned short h0 = f2bf(r0), h1 = f2bf(r1), h2 = f2bf(r2), h3 = f2bf(r3);
                u16x4 ph = { h0, h1, h2, h3 };
                u16x4 pl = { f2bf(r0 - bf2f(h0)), f2bf(r1 - bf2f(h1)),
                             f2bf(r2 - bf2f(h2)), f2bf(r3 - bf2f(h3)) };
                size_t off = ((size_t)(b * 16 + h) * 2048 + s) * 128 + dd;
                *(u16x4*)&OH[off] = ph;
                *(u16x4*)&OL[off] = pl;
            }
        }
    } else if constexpr (MODE == 2) {
        unsigned short* O = (unsigned short*)OutH;
#pragma unroll
        for (int mi = 0; mi < 4; ++mi) {
            int i0 = bi * 128 + wm * 64 + mi * 16 + lg * 4;  // token, 4 consecutive
            int b = i0 >> 11, s = i0 & 2047;
#pragma unroll
            for (int ni = 0; ni < 4; ++ni) {
                int jj = bj * 128 + wn * 64 + ni * 16 + lr;  // dout
                int h = jj >> 7, dd = jj & 127;
                f32x4 v = acc[mi][ni];
                u16x4 pk = { f2bf(v[0]), f2bf(v[1]), f2bf(v[2]), f2bf(v[3]) };
                *(u16x4*)&O[((size_t)(b * 16 + h) * 128 + dd) * 2048 + s] = pk;
            }
        }
    } else {
        float* O = (float*)OutH;
#pragma unroll
        for (int mi = 0; mi < 4; ++mi) {
            int i0 = bi * 128 + wm * 64 + mi * 16 + lg * 4;  // dout, 4 consecutive
#pragma unroll
            for (int ni = 0; ni < 4; ++ni) {
                int jj = bj * 128 + wn * 64 + ni * 16 + lr;  // token
                *(f32x4*)&O[(size_t)jj * 2048 + i0] = acc[mi][ni];
            }
        }
    }
}

// ---------------- causal flash attention v2 ----------------
// 1024 blocks (remapped: long qt first, bh grouped per XCD); 4 waves;
// wave owns 32 q rows; KVBLK=32; K tiles XOR-swizzled ((row&7)<<4) via
// pre-swizzled global source + swizzled ds_read; dbuf issue-early staging.
__global__ __launch_bounds__(256)
void attn2(const unsigned short* __restrict__ Qh, const unsigned short* __restrict__ Ql,
           const unsigned short* __restrict__ Kh, const unsigned short* __restrict__ Kl,
           const unsigned short* __restrict__ Vt, unsigned short* __restrict__ Ob)
{
    const int bid = blockIdx.x;
    const int slot = bid >> 3;
    const int bh = (bid & 7) + 8 * (slot & 7);   // xcd-grouped by bh%8
    const int qt = 15 - (slot >> 3);             // longest blocks dispatch first
    const int tid = threadIdx.x;
    const int lane = tid & 63, w = tid >> 6;
    const int lg = lane >> 4, lr = lane & 15;

    __shared__ unsigned short Ksh[2][32 * 128];  // 8KB x2
    __shared__ unsigned short Ksl[2][32 * 128];
    __shared__ unsigned short Vs [2][128 * 32];  // [d][kv]
    __shared__ unsigned short Ps [4][32 * 32];   // per-wave P relay

    const int qbase = qt * 128 + w * 32;
    const int qmaxw = qbase + 31;

    bf16x8 qfh[2][4], qfl[2][4];
#pragma unroll
    for (int qg = 0; qg < 2; ++qg) {
        const size_t qoff = ((size_t)bh * 2048 + qbase + qg * 16 + lr) * 128;
#pragma unroll
        for (int kk = 0; kk < 4; ++kk) {
            qfh[qg][kk] = *(const bf16x8*)(Qh + qoff + kk * 32 + lg * 8);
            qfl[qg][kk] = *(const bf16x8*)(Ql + qoff + kk * 32 + lg * 8);
        }
    }

    f32x4 o[8][2];
#pragma unroll
    for (int i = 0; i < 8; ++i)
#pragma unroll
        for (int qg = 0; qg < 2; ++qg) o[i][qg] = f32x4{0.f, 0.f, 0.f, 0.f};
    float m_run[2] = { -1e30f, -1e30f }, l_run[2] = { 0.f, 0.f };

    const int nkv = 4 * (qt + 1);

    auto stage = [&](int t) {
        const int buf = t & 1;
        const int kv0 = t * 32;
#pragma unroll
        for (int q2 = 0; q2 < 2; ++q2) {
            const int seg = w * 2 + q2;                          // 0..7
            {   // K hi/lo: rows 256B -> swizzle granule ^ (row&7)
                const int row = seg * 4 + (lane >> 4);
                const int gcol = 8 * ((lane & 15) ^ (row & 7));
                const size_t gs = ((size_t)bh * 2048 + kv0 + row) * 128 + gcol;
                const int loff = seg * 512 + lane * 8;
                gl16(Kh + gs, &Ksh[buf][loff]);
                gl16(Kl + gs, &Ksl[buf][loff]);
            }
            {   // V: rows 64B -> swizzle granule ^ (row&3)
                const int row = seg * 16 + (lane >> 2);          // d 0..127
                const int gcol = 8 * ((lane & 3) ^ (row & 3));
                const size_t gs = ((size_t)bh * 128 + row) * 2048 + kv0 + gcol;
                gl16(Vt + gs, &Vs[buf][seg * 512 + lane * 8]);
            }
        }
    };

    stage(0);
    __syncthreads();

#pragma unroll 1
    for (int t = 0; t < nkv; ++t) {
        if (t + 1 < nkv) stage(t + 1);           // issue-early into other buffer
        const int buf = t & 1;
        const int kv0 = t * 32;
        if (kv0 <= qmaxw) {
            f32x4 sc[2][2];
#pragma unroll
            for (int m2 = 0; m2 < 2; ++m2)
#pragma unroll
                for (int qg = 0; qg < 2; ++qg) sc[m2][qg] = f32x4{0.f, 0.f, 0.f, 0.f};
#pragma unroll
            for (int m2 = 0; m2 < 2; ++m2)
#pragma unroll
                for (int kk = 0; kk < 4; ++kk) {
                    const int go = 8 * ((4 * kk + lg) ^ (lr & 7));
                    bf16x8 kfh = *(const bf16x8*)&Ksh[buf][(m2 * 16 + lr) * 128 + go];
                    bf16x8 kfl = *(const bf16x8*)&Ksl[buf][(m2 * 16 + lr) * 128 + go];
#pragma unroll
                    for (int qg = 0; qg < 2; ++qg) {
                        sc[m2][qg] = __builtin_amdgcn_mfma_f32_16x16x32_bf16(kfh, qfh[qg][kk], sc[m2][qg], 0, 0, 0);
                        sc[m2][qg] = __builtin_amdgcn_mfma_f32_16x16x32_bf16(kfh, qfl[qg][kk], sc[m2][qg], 0, 0, 0);
                        sc[m2][qg] = __builtin_amdgcn_mfma_f32_16x16x32_bf16(kfl, qfh[qg][kk], sc[m2][qg], 0, 0, 0);
                    }
                }
#pragma unroll
            for (int qg = 0; qg < 2; ++qg) {
                const int q = qbase + qg * 16 + lr;
                float pmax = -1e30f;
#pragma unroll
                for (int m2 = 0; m2 < 2; ++m2)
#pragma unroll
                    for (int rr = 0; rr < 4; ++rr) {
                        int kvg = kv0 + m2 * 16 + lg * 4 + rr;
                        float sv = (kvg <= q) ? sc[m2][qg][rr] : -1e30f;
                        sc[m2][qg][rr] = sv;
                        pmax = fmaxf(pmax, sv);
                    }
                pmax = fmaxf(pmax, __shfl_xor(pmax, 16));
                pmax = fmaxf(pmax, __shfl_xor(pmax, 32));
                float mnew = fmaxf(m_run[qg], pmax);
                float alpha = __expf(m_run[qg] - mnew);
                float psum = 0.f;
                u16x4 pq[2];
#pragma unroll
                for (int m2 = 0; m2 < 2; ++m2)
#pragma unroll
                    for (int rr = 0; rr < 4; ++rr) {
                        float p = __expf(sc[m2][qg][rr] - mnew);
                        unsigned short ph = f2bf(p);
                        pq[m2][rr] = ph;
                        psum += bf2f(ph);        // consistent with PV numerator
                    }
                m_run[qg] = mnew;
                l_run[qg] = l_run[qg] * alpha + psum;
#pragma unroll
                for (int ni = 0; ni < 8; ++ni) {
                    o[ni][qg][0] *= alpha; o[ni][qg][1] *= alpha;
                    o[ni][qg][2] *= alpha; o[ni][qg][3] *= alpha;
                }
                *(u16x4*)&Ps[w][(qg * 16 + lr) * 32 + lg * 4]      = pq[0];
                *(u16x4*)&Ps[w][(qg * 16 + lr) * 32 + 16 + lg * 4] = pq[1];
            }
            bf16x8 pf0 = *(const bf16x8*)&Ps[w][lr * 32 + lg * 8];
            bf16x8 pf1 = *(const bf16x8*)&Ps[w][(16 + lr) * 32 + lg * 8];
#pragma unroll
            for (int ni = 0; ni < 8; ++ni) {
                bf16x8 vf = *(const bf16x8*)&Vs[buf][(ni * 16 + lr) * 32 + 8 * (lg ^ (lr & 3))];
                o[ni][0] = __builtin_amdgcn_mfma_f32_16x16x32_bf16(vf, pf0, o[ni][0], 0, 0, 0);
                o[ni][1] = __builtin_amdgcn_mfma_f32_16x16x32_bf16(vf, pf1, o[ni][1], 0, 0, 0);
            }
        }
        __syncthreads();
    }

    const int b = bh >> 4, h = bh & 15;
#pragma unroll
    for (int qg = 0; qg < 2; ++qg) {
        float l = l_run[qg];
        l += __shfl_xor(l, 16);
        l += __shfl_xor(l, 32);
        float inv = 1.f / l;
        const int q = qbase + qg * 16 + lr;
        unsigned short* Op = Ob + (((size_t)(b * 2048 + q) * 16 + h) * 128);
#pragma unroll
        for (int ni = 0; ni < 8; ++ni) {
            u16x4 pk = { f2bf(o[ni][qg][0] * inv), f2bf(o[ni][qg][1] * inv),
                         f2bf(o[ni][qg][2] * inv), f2bf(o[ni][qg][3] * inv) };
            *(u16x4*)&Op[ni * 16 + lg * 4] = pk;
        }
    }
}

extern "C" void kernel_launch(void* const* d_in, const int* in_sizes, int n_in,
                              void* d_out, int out_size, void* d_ws, size_t ws_size,
                              hipStream_t stream) {
    const float* x  = (const float*)d_in[0];
    const float* Wq = (const float*)d_in[1];
    const float* Wk = (const float*)d_in[2];
    const float* Wv = (const float*)d_in[3];
    const float* Wo = (const float*)d_in[4];

    char* ws = (char*)d_ws;
    float* cosT = (float*)ws;                                   // 512 KB
    float* sinT = cosT + 2048 * 64;                             // 512 KB
    unsigned short* xh  = (unsigned short*)(ws + (1 << 20));    // 32 MB
    unsigned short* xl  = xh  + (size_t)16777216;               // 32 MB
    unsigned short* Wvh = xl  + (size_t)16777216;               // 8 MB
    unsigned short* Ql  = Wvh + (size_t)4194304;                // 32 MB
    unsigned short* Kl  = Ql  + (size_t)16777216;               // 32 MB  (ws ~137 MB)

    // aliases (lifetimes disjoint): Vt overwrites xl after K-GEMM;
    // attn_b overwrites xh after V-GEMM.
    unsigned short* Vt     = xl;
    unsigned short* attn_b = xh;

    // d_out (67 MB fp32) hosts Qh/Kh until the final GEMM overwrites it
    unsigned short* Qh = (unsigned short*)d_out;
    unsigned short* Kh = Qh + (size_t)16777216;

    rope_tables<<<dim3(512), 256, 0, stream>>>(cosT, sinT);
    presplit<<<dim3(16384), 256, 0, stream>>>(x, xh, xl, 4194304);
    presplit<<<dim3(4096), 256, 0, stream>>>(Wv, Wvh, nullptr, 1048576);

    gemm2<0><<<dim3(16, 64), 256, 0, stream>>>(Wq, nullptr, xh, xl, Qh, Ql, cosT, sinT);
    gemm2<1><<<dim3(16, 64), 256, 0, stream>>>(Wk, nullptr, xh, xl, Kh, Kl, cosT, sinT);
    gemm2<2><<<dim3(64, 16), 256, 0, stream>>>(nullptr, xh, Wvh, nullptr, Vt, nullptr, cosT, sinT);
    attn2<<<dim3(1024), 256, 0, stream>>>(Qh, Ql, Kh, Kl, Vt, attn_b);
    gemm2<3><<<dim3(16, 64), 256, 0, stream>>>(Wo, nullptr, attn_b, nullptr, d_out, nullptr, cosT, sinT);
}